// Round 5
// baseline (36.542 us; speedup 1.0000x reference)
//
#include <hip/hip_runtime.h>

#define NS 128
#define NX 512
#define NY 512
#define NT 2048

// ===== NUMERICS CONTRACT (hard-won; R2/R4 failed, R0/R3 passed) =====
// The reference's interp  w0*x[i0] + (1-w0)*x[i0+1]  is DISCONTINUOUS at
// integer idx, so floor(idx) must match the np reference bit-for-bit.
// The passing idx recipe (R3, verbatim):
//     dx = g.x - sv.x;  dy = g.y - sv.y;
//     dist = sqrtf(dx*dx + dy*dy);            // libm, correctly rounded
//     idx  = dist * (1.0f/1500.0f) * (1.0f/4e-08f);
// Forbidden: folded scales inside sqrt, hand-rolled sqrt refinement,
// packed/vectorized float2 geometry math, fract intrinsics, misaligned
// float2 gathers. Accumulation FORM is free (tolerance 0.895).
//
// Fast path below uses raw v_sqrt_f32 (<=1 ulp). |idx_fast - idx_exact|
// <= ~5e-4, so when fract(idx_fast) is not within EPS=1e-3 of a boundary
// the floor decision provably equals the exact one; ambiguous lanes
// recompute through the trusted libm sqrtf on the SAME d2.
#define EPS_GUARD 1e-3f

__global__ __launch_bounds__(256, 8) void das_kernel(
        const float* __restrict__ x,        // (NS, NT)
        const float* __restrict__ sensors,  // (NS, 2)
        const float* __restrict__ grid,     // (P, 2)
        float* __restrict__ out) {          // (P,)
    const int tid = threadIdx.x;
    const int lane = tid & 63;
    const int wave = tid >> 6;          // 0..3
    const int tile = wave & 1;          // 2 pixel tiles per block
    const int half = wave >> 1;         // sensor half (0: s<64, 1: s>=64)

    // 8x8 pixel tile per wave -> gather lane-spread ~2 cache lines
    const int tileIdx = blockIdx.x * 2 + tile;
    const int ti = tileIdx >> 6;
    const int tj = tileIdx & 63;
    const int i = ti * 8 + (lane >> 3);
    const int j = tj * 8 + (lane & 7);
    const int p = i * NY + j;

    const float2 g = reinterpret_cast<const float2*>(grid)[p];

    const float inv_c = 1.0f / 1500.0f;
    const float inv_dt = 1.0f / 4e-08f;

    float acc = 0.0f;
#pragma unroll 8
    for (int s = 0; s < 64; ++s) {
        // wave-uniform sensor index -> scalar loads (s_load) for coords/row base
        const int sidx = __builtin_amdgcn_readfirstlane(half * 64 + s);
        const float2 sv = reinterpret_cast<const float2*>(sensors)[sidx];
        const float dx = g.x - sv.x;
        const float dy = g.y - sv.y;
        const float d2 = dx * dx + dy * dy;            // same expr shape as R3

        // fast idx: single v_sqrt_f32 (<=1 ulp)
        const float idx_f = __builtin_amdgcn_sqrtf(d2) * inv_c * inv_dt;
        float d0 = floorf(idx_f);
        float w0 = idx_f - d0;
        if (w0 < EPS_GUARD || w0 > 1.0f - EPS_GUARD) {
            // ambiguous floor: recompute with the exact frozen recipe
            const float dist = sqrtf(d2);              // numerics-frozen
            const float idx_e = dist * inv_c * inv_dt; // numerics-frozen
            d0 = floorf(idx_e);
            w0 = idx_e - d0;
        }
        const int i0 = (int)d0;

        const float* row = x + sidx * NT;              // SGPR base
        const float y0 = row[i0];                      // shared vaddr,
        const float y1 = row[i0 + 1];                  // offset:4 fold
        acc = fmaf(w0, y0, acc);
        acc = fmaf(1.0f - w0, y1, acc);
    }

    __shared__ float part[256];
    part[tid] = acc;
    __syncthreads();
    // waves 0,1 (half 0) combine with waves 2,3 (half 1), same tile & lane
    if (tid < 128) out[p] = acc + part[tid + 128];
}

extern "C" void kernel_launch(void* const* d_in, const int* in_sizes, int n_in,
                              void* d_out, int out_size, void* d_ws, size_t ws_size,
                              hipStream_t stream) {
    const float* x = (const float*)d_in[0];        // (1, NS, NT)
    const float* sensors = (const float*)d_in[1];  // (NS, 2)
    const float* grid = (const float*)d_in[2];     // (P, 2)
    float* out = (float*)d_out;                    // (1, NX, NY)

    const int nTiles = (NX / 8) * (NY / 8);        // 4096
    const int nblocks = nTiles / 2;                // 2048 blocks * 256 threads
    das_kernel<<<nblocks, 256, 0, stream>>>(x, sensors, grid, out);
}

// Round 6
// 30.042 us; speedup vs baseline: 1.2164x; 1.2164x over previous
//
#include <hip/hip_runtime.h>

#define NS 128
#define NX 512
#define NY 512
#define NT 2048

// ===== NUMERICS CONTRACT (hard-won; R2/R4 failed, R0/R3/R5 passed) =====
// The reference's interp  w0*x[i0] + (1-w0)*x[i0+1]  is DISCONTINUOUS at
// integer idx, so floor(idx) must match the np reference bit-for-bit.
// The passing idx recipe (R3, verbatim — DO NOT TOUCH):
//     dx = g.x - sv.x;  dy = g.y - sv.y;
//     dist = sqrtf(dx*dx + dy*dy);            // libm, correctly rounded
//     idx  = dist * (1.0f/1500.0f) * (1.0f/4e-08f);
// Forbidden (each failed a round): folded scales inside sqrt (R2),
// hand-rolled sqrt refinement (R4), packed float2 geometry math (R4),
// fract intrinsics (R4), fast-sqrt + boundary guard (R5: correct but
// SLOWER — branch overhead > sqrtf fixup cost).
// Accumulation FORM is free (tolerance 0.895 vs ~1e-5 jitter).

__global__ __launch_bounds__(256, 8) void das_kernel(
        const float* __restrict__ x,        // (NS, NT)
        const float* __restrict__ sensors,  // (NS, 2)
        const float* __restrict__ grid,     // (P, 2)
        float* __restrict__ out) {          // (P,)
    const int tid = threadIdx.x;
    const int lane = tid & 63;
    const int wave = tid >> 6;              // 0..3 = sensor quarter

    // one 8x8 pixel tile per BLOCK; all 4 waves share it (lane -> pixel)
    const int tileIdx = blockIdx.x;         // 4096 tiles
    const int ti = tileIdx >> 6;
    const int tj = tileIdx & 63;
    const int i = ti * 8 + (lane >> 3);
    const int j = tj * 8 + (lane & 7);
    const int p = i * NY + j;

    const float2 g = reinterpret_cast<const float2*>(grid)[p];

    const float inv_c = 1.0f / 1500.0f;
    const float inv_dt = 1.0f / 4e-08f;

    // wave-uniform sensor base, hoisted: coords via s_load at imm offsets,
    // row bases via scalar adds.
    const int sbase = __builtin_amdgcn_readfirstlane(wave << 5);
    const float2* svp = reinterpret_cast<const float2*>(sensors) + sbase;
    const float* xrow0 = x + sbase * NT;

    float accA = 0.0f, accB = 0.0f;         // two chains for ILP
#pragma unroll 8
    for (int s = 0; s < 32; ++s) {
        const float2 sv = svp[s];
        const float dx = g.x - sv.x;
        const float dy = g.y - sv.y;
        const float dist = sqrtf(dx * dx + dy * dy);   // FROZEN
        const float idx = dist * inv_c * inv_dt;       // FROZEN
        const float d0 = floorf(idx);
        const float w0 = idx - d0;
        const int i0 = (int)d0;
        const float* row = xrow0 + s * NT;             // SGPR base
        const float y0 = row[i0];                      // shared vaddr,
        const float y1 = row[i0 + 1];                  // offset:4 fold
        accA = fmaf(w0, y0 - y1, accA);                // y1 + w0*(y0-y1) form
        accB += y1;
    }
    const float acc = accA + accB;

    __shared__ float part[256];
    part[tid] = acc;
    __syncthreads();
    if (tid < 64)
        out[p] = part[tid] + part[tid + 64] + part[tid + 128] + part[tid + 192];
}

extern "C" void kernel_launch(void* const* d_in, const int* in_sizes, int n_in,
                              void* d_out, int out_size, void* d_ws, size_t ws_size,
                              hipStream_t stream) {
    const float* x = (const float*)d_in[0];        // (1, NS, NT)
    const float* sensors = (const float*)d_in[1];  // (NS, 2)
    const float* grid = (const float*)d_in[2];     // (P, 2)
    float* out = (float*)d_out;                    // (1, NX, NY)

    const int nTiles = (NX / 8) * (NY / 8);        // 4096 blocks, 4 waves each
    das_kernel<<<nTiles, 256, 0, stream>>>(x, sensors, grid, out);
}

// Round 7
// 26.905 us; speedup vs baseline: 1.3582x; 1.1166x over previous
//
#include <hip/hip_runtime.h>

#define NS 128
#define NX 512
#define NY 512
#define NT 2048

// ===== NUMERICS CONTRACT (R2/R4 failed, R0/R3/R5/R6 passed) =====
// floor(idx) must match the np reference everywhere; idx recipe:
//     dist = CORRECTLY-ROUNDED sqrt(dx*dx + dy*dy);   // RN, unique
//     idx  = dist * (1.0f/1500.0f) * (1.0f/4e-08f);   // two separate muls
// Forbidden: folded scale inside sqrt (R2), raw 1-ulp v_sqrt for idx (R2),
// packed float2 geometry (R4 — changes d2 contraction), any change to the
// d2 expression text. w0/accumulation FORM is free (tolerance 0.895).
//
// THIS ROUND'S single numerics experiment: sqrt_cr below = LLVM's own
// lowerFSQRTF32 Tuckerman core minus the denormal-scaling/special-case
// guards (d2 in [4.7e-4, 6.3e-3] is always normal finite positive).
// CR sqrt is unique, so this must be bit-identical to libm sqrtf here.

__device__ __forceinline__ float sqrt_cr(float x) {
    const float r0 = __builtin_amdgcn_sqrtf(x);               // <=1 ulp
    const float rd = __int_as_float(__float_as_int(r0) - 1);  // r0 - 1ulp
    const float ru = __int_as_float(__float_as_int(r0) + 1);  // r0 + 1ulp
    const float vd = fmaf(-rd, r0, x);   // x - rd*r0  (exact fma fence test)
    const float vu = fmaf(-ru, r0, x);   // x - ru*r0
    float r = (vd <= 0.0f) ? rd : r0;    // x <= rd*r0  -> round down
    r = (vu > 0.0f) ? ru : r;            // x >  ru*r0  -> round up
    return r;
}

__global__ __launch_bounds__(256, 8) void das_kernel(
        const float* __restrict__ x,        // (NS, NT)
        const float* __restrict__ sensors,  // (NS, 2)
        const float* __restrict__ grid,     // (P, 2)
        float* __restrict__ out) {          // (P,)
    const int tid = threadIdx.x;
    const int lane = tid & 63;
    const int wave = tid >> 6;              // 0..3 = sensor quarter

    // one 8x8 pixel tile per block; all 4 waves share it (lane -> pixel)
    const int tileIdx = blockIdx.x;         // 4096 tiles
    const int ti = tileIdx >> 6;
    const int tj = tileIdx & 63;
    const int i = ti * 8 + (lane >> 3);
    const int j = tj * 8 + (lane & 7);
    const int p = i * NY + j;

    const float2 g = reinterpret_cast<const float2*>(grid)[p];

    const float inv_c = 1.0f / 1500.0f;
    const float inv_dt = 1.0f / 4e-08f;

    // wave-uniform sensor base; full unroll lets the compiler hoist all 32
    // s_load_dwordx2 sensor-coord loads out of the loop (SGPR-resident).
    const int sbase = __builtin_amdgcn_readfirstlane(wave << 5);
    const float2* svp = reinterpret_cast<const float2*>(sensors) + sbase;
    const float* xrow0 = x + sbase * NT;

    float accA = 0.0f, accB = 0.0f;         // two chains for ILP
#pragma unroll
    for (int s = 0; s < 32; ++s) {
        const float2 sv = svp[s];                      // uniform -> s_load
        const float dx = g.x - sv.x;
        const float dy = g.y - sv.y;
        const float dist = sqrt_cr(dx * dx + dy * dy); // d2 text as R6
        const float idx = dist * inv_c * inv_dt;       // FROZEN two muls
        const int i0 = (int)idx;                       // trunc == floor (idx>0)
        const float w0 = __builtin_amdgcn_fractf(idx); // == idx - floor(idx)
        const float* row = xrow0 + s * NT;             // SGPR base per sensor
        const float y0 = row[i0];                      // shared vaddr,
        const float y1 = row[i0 + 1];                  // offset:4 fold
        accA = fmaf(w0, y0 - y1, accA);                // y1 + w0*(y0-y1) form
        accB += y1;
    }
    const float acc = accA + accB;

    __shared__ float part[256];
    part[tid] = acc;
    __syncthreads();
    if (tid < 64)
        out[p] = part[tid] + part[tid + 64] + part[tid + 128] + part[tid + 192];
}

extern "C" void kernel_launch(void* const* d_in, const int* in_sizes, int n_in,
                              void* d_out, int out_size, void* d_ws, size_t ws_size,
                              hipStream_t stream) {
    const float* x = (const float*)d_in[0];        // (1, NS, NT)
    const float* sensors = (const float*)d_in[1];  // (NS, 2)
    const float* grid = (const float*)d_in[2];     // (P, 2)
    float* out = (float*)d_out;                    // (1, NX, NY)

    const int nTiles = (NX / 8) * (NY / 8);        // 4096 blocks, 4 waves each
    das_kernel<<<nTiles, 256, 0, stream>>>(x, sensors, grid, out);
}

// Round 8
// 24.488 us; speedup vs baseline: 1.4922x; 1.0987x over previous
//
#include <hip/hip_runtime.h>

#define NS 128
#define NX 512
#define NY 512
#define NT 2048

// ===== NUMERICS CONTRACT (R2/R4 failed; R0/R3/R5/R6/R7 passed) =====
// floor(idx) must match the np reference everywhere; idx recipe:
//     dist = CORRECTLY-ROUNDED sqrt(dx*dx + dy*dy);   // RN, unique
//     idx  = dist * (1.0f/1500.0f) * (1.0f/4e-08f);   // two separate muls
// sqrt_cr below (LLVM lowerFSQRTF32 Tuckerman core, guards stripped) was
// proven bit-exact in R7 (absmax 0.0625, the best band). Forbidden: folded
// scale inside sqrt (R2), raw 1-ulp v_sqrt for idx (R2), packed float2
// geometry (R4), changing the d2 expression text. Accum FORM is free.

__device__ __forceinline__ float sqrt_cr(float x) {
    const float r0 = __builtin_amdgcn_sqrtf(x);               // <=1 ulp
    const float rd = __int_as_float(__float_as_int(r0) - 1);  // r0 - 1ulp
    const float ru = __int_as_float(__float_as_int(r0) + 1);  // r0 + 1ulp
    const float vd = fmaf(-rd, r0, x);
    const float vu = fmaf(-ru, r0, x);
    float r = (vd <= 0.0f) ? rd : r0;
    r = (vu > 0.0f) ? ru : r;
    return r;
}

// 2 pixels per lane (j and j+8): two independent geometry->gather chains
// double in-flight loads and fill each other's latency bubbles.
__global__ __launch_bounds__(256, 8) void das_kernel(
        const float* __restrict__ x,        // (NS, NT)
        const float* __restrict__ sensors,  // (NS, 2)
        const float* __restrict__ grid,     // (P, 2)
        float* __restrict__ out) {          // (P,)
    const int tid = threadIdx.x;
    const int lane = tid & 63;
    const int wave = tid >> 6;              // 0..3 = sensor quarter

    // 8x16-pixel tile per block; lane covers (i, j) and (i, j+8)
    const int tileIdx = blockIdx.x;         // 2048 tiles
    const int ti = tileIdx >> 5;            // 0..63
    const int tjj = tileIdx & 31;           // 0..31
    const int i = ti * 8 + (lane >> 3);
    const int j = tjj * 16 + (lane & 7);
    const int p0 = i * NY + j;
    const int p1 = p0 + 8;

    const float2 g0 = reinterpret_cast<const float2*>(grid)[p0];
    const float2 g1 = reinterpret_cast<const float2*>(grid)[p1];

    const float inv_c = 1.0f / 1500.0f;
    const float inv_dt = 1.0f / 4e-08f;

    // wave-uniform sensor base; full unroll hoists sensor s_loads
    const int sbase = __builtin_amdgcn_readfirstlane(wave << 5);
    const float2* svp = reinterpret_cast<const float2*>(sensors) + sbase;
    const float* xrow0 = x + sbase * NT;

    float accA0 = 0.0f, accB0 = 0.0f, accA1 = 0.0f, accB1 = 0.0f;
#pragma unroll
    for (int s = 0; s < 32; ++s) {
        const float2 sv = svp[s];                      // uniform -> s_load
        const float* row = xrow0 + s * NT;             // SGPR base

        const float dx0 = g0.x - sv.x;
        const float dy0 = g0.y - sv.y;
        const float dist0 = sqrt_cr(dx0 * dx0 + dy0 * dy0);  // FROZEN DAG
        const float idx0 = dist0 * inv_c * inv_dt;           // FROZEN
        const int i00 = (int)idx0;
        const float w00 = __builtin_amdgcn_fractf(idx0);
        const float y00 = row[i00];
        const float y01 = row[i00 + 1];

        const float dx1 = g1.x - sv.x;
        const float dy1 = g1.y - sv.y;
        const float dist1 = sqrt_cr(dx1 * dx1 + dy1 * dy1);  // FROZEN DAG
        const float idx1 = dist1 * inv_c * inv_dt;           // FROZEN
        const int i10 = (int)idx1;
        const float w10 = __builtin_amdgcn_fractf(idx1);
        const float y10 = row[i10];
        const float y11 = row[i10 + 1];

        accA0 = fmaf(w00, y00 - y01, accA0);
        accB0 += y01;
        accA1 = fmaf(w10, y10 - y11, accA1);
        accB1 += y11;
    }
    const float acc0 = accA0 + accB0;
    const float acc1 = accA1 + accB1;

    __shared__ float part[2][256];
    part[0][tid] = acc0;
    part[1][tid] = acc1;
    __syncthreads();
    const int rl = tid & 63;
    const int ri = ti * 8 + (rl >> 3);
    const int rj = tjj * 16 + (rl & 7);
    const int rp = ri * NY + rj;
    if (tid < 64)
        out[rp] = part[0][rl] + part[0][rl + 64] + part[0][rl + 128] + part[0][rl + 192];
    else if (tid < 128)
        out[rp + 8] = part[1][rl] + part[1][rl + 64] + part[1][rl + 128] + part[1][rl + 192];
}

extern "C" void kernel_launch(void* const* d_in, const int* in_sizes, int n_in,
                              void* d_out, int out_size, void* d_ws, size_t ws_size,
                              hipStream_t stream) {
    const float* x = (const float*)d_in[0];        // (1, NS, NT)
    const float* sensors = (const float*)d_in[1];  // (NS, 2)
    const float* grid = (const float*)d_in[2];     // (P, 2)
    float* out = (float*)d_out;                    // (1, NX, NY)

    const int nTiles = (NX / 8) * (NY / 16);       // 2048 blocks, 4 waves each
    das_kernel<<<nTiles, 256, 0, stream>>>(x, sensors, grid, out);
}